// Round 4
// baseline (225.696 us; speedup 1.0000x reference)
//
#include <hip/hip_runtime.h>
#include <hip/hip_bf16.h>
#include <stdint.h>

// FlexHNN fused forward, MI355X gfx950 — fully in-register layer chaining.
// N=131072 rows, DZ=16, H=256. bf16 MFMA (16x16x32, fp32 acc), weights
// pre-permuted so D-frag of layer L packs directly into B-frag of layer L+1:
//   khid(s,kg,j) = 32*s + 16*(j>>2) + 4*kg + (j&3)
// Each wave owns 32 batch rows (two 16-col B strips sharing every A-frag
// load). No __syncthreads in the main kernel; no inter-wave data sharing.
//
// ws layout (bf16 elems / unsigned short):
//   [0,      8192)  w1hp: [16 ob][64 lane][8]  hW1 A-frags (k 16->32 zero-pad)
//   [8192,  16384)  w1fp: same for fW1
//   [16384, 81920)  w2hp: [16 ob][8 s][64][8]  hW2 A-frags, khid-permuted
//   [81920,147456)  w2fp: same for fW2
//   [147456,151552) w3fp: [8 s][64][8]         fW3 A-frags, khid-permuted
// total 151552 shorts = 303104 B.

typedef __attribute__((ext_vector_type(8))) short short8;       // 8 bf16 (4 VGPR)
typedef __attribute__((ext_vector_type(4))) float floatx4;      // MFMA C/D
typedef __attribute__((ext_vector_type(4))) unsigned int uintx4;

static __device__ __forceinline__ unsigned short f2bf(float x) {
  union { float f; uint32_t u; } v; v.f = x;
  return (unsigned short)((v.u + 0x7FFFu + ((v.u >> 16) & 1u)) >> 16);  // RNE
}
static __device__ __forceinline__ uint32_t packpair(float a, float b) {
  return (uint32_t)f2bf(a) | ((uint32_t)f2bf(b) << 16);
}
static __device__ __forceinline__ float unpklo(uint32_t u) {
  union { uint32_t u; float f; } v; v.u = u << 16;
  return v.f;
}
static __device__ __forceinline__ float unpkhi(uint32_t u) {
  union { uint32_t u; float f; } v; v.u = u & 0xffff0000u;
  return v.f;
}
// clamped Pade(7,6) tanh: max err ~7e-4, pure FMA + one v_rcp_f32
static __device__ __forceinline__ float tanh_fast(float x) {
  float cx = fminf(4.0f, fmaxf(-4.0f, x));
  float x2 = cx * cx;
  float num = cx * (135135.0f + x2 * (17325.0f + x2 * (378.0f + x2)));
  float den = 135135.0f + x2 * (62370.0f + x2 * (3150.0f + 28.0f * x2));
  return num * __builtin_amdgcn_rcpf(den);
}
static __device__ __forceinline__ floatx4 mfma16(short8 a, short8 b, floatx4 c) {
  return __builtin_amdgcn_mfma_f32_16x16x32_bf16(a, b, c, 0, 0, 0);
}
static __device__ __forceinline__ short8 asfrag(uintx4 u) {
  union { uintx4 u; short8 s; } v; v.u = u;
  return v.s;
}

__global__ __launch_bounds__(256) void prep_kernel(
    const float* __restrict__ hW1, const float* __restrict__ hW2,
    const float* __restrict__ fW1, const float* __restrict__ fW2,
    const float* __restrict__ fW3, unsigned short* __restrict__ ws) {
  int i = blockIdx.x * 256 + threadIdx.x;  // grid covers [0, 65536)
  {
    int ob = i >> 12, s = (i >> 9) & 7, lane = (i >> 3) & 63, j = i & 7;
    int m = ob * 16 + (lane & 15), kg = lane >> 4;
    int k = 32 * s + 16 * (j >> 2) + 4 * kg + (j & 3);   // khid permutation
    ws[16384 + i] = f2bf(hW2[m * 256 + k]);
    ws[81920 + i] = f2bf(fW2[m * 256 + k]);
  }
  if (i < 8192) {
    int ob = i >> 9, lane = (i >> 3) & 63, j = i & 7;
    int m = ob * 16 + (lane & 15), kg = lane >> 4;
    unsigned short vh = 0, vf = 0;
    if (kg < 2) { int k = kg * 8 + j; vh = f2bf(hW1[m * 16 + k]); vf = f2bf(fW1[m * 16 + k]); }
    ws[i] = vh;
    ws[8192 + i] = vf;
  }
  if (i < 4096) {
    int s = i >> 9, lane = (i >> 3) & 63, j = i & 7;
    int m = lane & 15, kg = lane >> 4;
    int k = 32 * s + 16 * (j >> 2) + 4 * kg + (j & 3);
    ws[147456 + i] = f2bf(fW3[m * 256 + k]);
  }
}

__global__ __launch_bounds__(256, 2) void flexhnn_kernel(
    const float* __restrict__ z,
    const float* __restrict__ hb1, const float* __restrict__ hb2,
    const float* __restrict__ fb1, const float* __restrict__ fb2,
    const float* __restrict__ fb3,
    const unsigned short* __restrict__ ws,
    float* __restrict__ out) {
  // per-wave private s1 stash: [wave][strip][i=ob*2+p][lane] dwords, 64 KiB.
  // bank = lane%32 -> 2 lanes/bank (free). No barriers anywhere.
  __shared__ uint32_t s1_lds[4][2][32][64];

  const int tid = threadIdx.x, lane = tid & 63, wave = tid >> 6;
  const int c = lane & 15, kg = lane >> 4;
  const int b0 = (blockIdx.x * 4 + wave) * 32;

  const unsigned short* w1hp = ws;
  const unsigned short* w1fp = ws + 8192;
  const unsigned short* w2hp = ws + 16384;
  const unsigned short* w2fp = ws + 81920;
  const unsigned short* w3fp = ws + 147456;

  // ---- z B-frags for the two strips (K=16 zero-padded to 32) ----
  short8 zf[2];
  zf[0] = (short8){0,0,0,0,0,0,0,0};
  zf[1] = (short8){0,0,0,0,0,0,0,0};
  if (kg < 2) {
#pragma unroll
    for (int st = 0; st < 2; ++st) {
      const float* zr = z + (size_t)(b0 + st * 16 + c) * 16 + kg * 8;
      uintx4 u;
      u.x = packpair(zr[0], zr[1]); u.y = packpair(zr[2], zr[3]);
      u.z = packpair(zr[4], zr[5]); u.w = packpair(zr[6], zr[7]);
      zf[st] = asfrag(u);
    }
  }

  // ---- phase 1: a1 = z@hW1^T; t1 -> B-frags (regs), s1 -> private LDS ----
  uintx4 t1v[2][8];
#pragma unroll
  for (int ob = 0; ob < 16; ++ob) {
    short8 wf = *reinterpret_cast<const short8*>(w1hp + (ob * 64 + lane) * 8);
    floatx4 bias = *reinterpret_cast<const floatx4*>(hb1 + ob * 16 + kg * 4);
#pragma unroll
    for (int st = 0; st < 2; ++st) {
      floatx4 a = mfma16(wf, zf[st], bias);
      float t0 = tanh_fast(a[0]), t1_ = tanh_fast(a[1]);
      float t2 = tanh_fast(a[2]), t3 = tanh_fast(a[3]);
      t1v[st][ob >> 1][(ob & 1) * 2 + 0] = packpair(t0, t1_);
      t1v[st][ob >> 1][(ob & 1) * 2 + 1] = packpair(t2, t3);
      s1_lds[wave][st][ob * 2 + 0][lane] = packpair(1.0f - t0 * t0, 1.0f - t1_ * t1_);
      s1_lds[wave][st][ob * 2 + 1][lane] = packpair(1.0f - t2 * t2, 1.0f - t3 * t3);
    }
  }

  // ---- phase 2: a2 = t1@hW2^T (s2 transient); f1 = z@fW1^T; fmix -> frags ----
  uintx4 fmv[2][8];
#pragma unroll
  for (int ob = 0; ob < 16; ++ob) {
    floatx4 b2 = *reinterpret_cast<const floatx4*>(hb2 + ob * 16 + kg * 4);
    floatx4 a[2] = {b2, b2};
#pragma unroll
    for (int s = 0; s < 8; ++s) {
      short8 wf = *reinterpret_cast<const short8*>(w2hp + ((ob * 8 + s) * 64 + lane) * 8);
      a[0] = mfma16(wf, asfrag(t1v[0][s]), a[0]);
      a[1] = mfma16(wf, asfrag(t1v[1][s]), a[1]);
    }
    short8 w1 = *reinterpret_cast<const short8*>(w1fp + (ob * 64 + lane) * 8);
    floatx4 bf1 = *reinterpret_cast<const floatx4*>(fb1 + ob * 16 + kg * 4);
#pragma unroll
    for (int st = 0; st < 2; ++st) {
      floatx4 f = mfma16(w1, zf[st], bf1);
      float fm[4];
#pragma unroll
      for (int r = 0; r < 4; ++r) {
        float t2 = tanh_fast(a[st][r]);
        float s2 = 1.0f - t2 * t2;
        float fv = f[r];
        fm[r] = 0.5f * (fv * s2 + tanh_fast(fv));
      }
      fmv[st][ob >> 1][(ob & 1) * 2 + 0] = packpair(fm[0], fm[1]);
      fmv[st][ob >> 1][(ob & 1) * 2 + 1] = packpair(fm[2], fm[3]);
    }
  }

  // ---- phase 3: f2 = fmix@fW2^T; fmix2 = 0.5*(f2*s1 + tanh(f2)) -> frags ----
  uintx4 gv[2][8];
#pragma unroll
  for (int ob = 0; ob < 16; ++ob) {
    floatx4 bf2 = *reinterpret_cast<const floatx4*>(fb2 + ob * 16 + kg * 4);
    floatx4 a[2] = {bf2, bf2};
#pragma unroll
    for (int s = 0; s < 8; ++s) {
      short8 wf = *reinterpret_cast<const short8*>(w2fp + ((ob * 8 + s) * 64 + lane) * 8);
      a[0] = mfma16(wf, asfrag(fmv[0][s]), a[0]);
      a[1] = mfma16(wf, asfrag(fmv[1][s]), a[1]);
    }
#pragma unroll
    for (int st = 0; st < 2; ++st) {
      uint32_t sp0 = s1_lds[wave][st][ob * 2 + 0][lane];
      uint32_t sp1 = s1_lds[wave][st][ob * 2 + 1][lane];
      float s1a = unpklo(sp0), s1b = unpkhi(sp0), s1c = unpklo(sp1), s1d = unpkhi(sp1);
      float f0 = a[st][0], f1_ = a[st][1], f2_ = a[st][2], f3 = a[st][3];
      float g0 = 0.5f * (f0 * s1a + tanh_fast(f0));
      float g1 = 0.5f * (f1_ * s1b + tanh_fast(f1_));
      float g2 = 0.5f * (f2_ * s1c + tanh_fast(f2_));
      float g3 = 0.5f * (f3 * s1d + tanh_fast(f3));
      gv[st][ob >> 1][(ob & 1) * 2 + 0] = packpair(g0, g1);
      gv[st][ob >> 1][(ob & 1) * 2 + 1] = packpair(g2, g3);
    }
  }

  // ---- phase 4: f3 = fmix2@fW3^T (16 out rows); symplectic write ----
  {
    floatx4 b3 = *reinterpret_cast<const floatx4*>(fb3 + kg * 4);
    floatx4 o[2] = {b3, b3};
#pragma unroll
    for (int s = 0; s < 8; ++s) {
      short8 wf = *reinterpret_cast<const short8*>(w3fp + (s * 64 + lane) * 8);
      o[0] = mfma16(wf, asfrag(gv[0][s]), o[0]);
      o[1] = mfma16(wf, asfrag(gv[1][s]), o[1]);
    }
    // lane holds f rows o = 4*kg + r. o<8 -> out col o+8 = -f; o>=8 -> col o-8 = +f.
    const int off = (kg < 2) ? (kg * 4 + 8) : (kg * 4 - 8);
    const float sgn = (kg < 2) ? -1.0f : 1.0f;
#pragma unroll
    for (int st = 0; st < 2; ++st) {
      float4 stv;
      stv.x = sgn * o[st][0]; stv.y = sgn * o[st][1];
      stv.z = sgn * o[st][2]; stv.w = sgn * o[st][3];
      *reinterpret_cast<float4*>(out + (size_t)(b0 + st * 16 + c) * 16 + off) = stv;
    }
  }
}

extern "C" void kernel_launch(void* const* d_in, const int* in_sizes, int n_in,
                              void* d_out, int out_size, void* d_ws, size_t ws_size,
                              hipStream_t stream) {
  const float* z   = (const float*)d_in[1];
  const float* hW1 = (const float*)d_in[2];
  const float* hb1 = (const float*)d_in[3];
  const float* hW2 = (const float*)d_in[4];
  const float* hb2 = (const float*)d_in[5];
  const float* fW1 = (const float*)d_in[6];
  const float* fb1 = (const float*)d_in[7];
  const float* fW2 = (const float*)d_in[8];
  const float* fb2 = (const float*)d_in[9];
  const float* fW3 = (const float*)d_in[10];
  const float* fb3 = (const float*)d_in[11];
  unsigned short* ws = (unsigned short*)d_ws;
  float* out = (float*)d_out;

  hipLaunchKernelGGL(prep_kernel, dim3(256), dim3(256), 0, stream,
                     hW1, hW2, fW1, fW2, fW3, ws);
  // 131072 rows / (4 waves * 32 rows) = 1024 blocks
  hipLaunchKernelGGL(flexhnn_kernel, dim3(1024), dim3(256), 0, stream,
                     z, hb1, hb2, fb1, fb2, fb3, (const unsigned short*)ws, out);
}

// Round 7
// 186.614 us; speedup vs baseline: 1.2094x; 1.2094x over previous
//
#include <hip/hip_runtime.h>
#include <hip/hip_bf16.h>
#include <stdint.h>

// FlexHNN fused forward, MI355X gfx950 — in-register layer chaining +
// cooperative double-buffered LDS weight staging for the two K=256 GEMMs.
// N=131072 rows, DZ=16, H=256. bf16 MFMA (16x16x32, fp32 acc), weights
// pre-permuted so D-frag of layer L packs directly into B-frag of layer L+1:
//   khid(s,kg,j) = 32*s + 16*(j>>2) + 4*kg + (j&3)
// Each wave owns 32 batch rows (two 16-col B strips sharing every A-frag).
// Weight chunks (8 frags = 8 KB per ob) are staged block-cooperatively via
// global_load_lds into a 2x8KB double buffer: stage(t+1) -> process(t) ->
// __syncthreads. One barrier per ob; prefetch drains under the process phase.
//
// ws layout (bf16 elems / unsigned short):
//   [0,      8192)  w1hp: [16 ob][64 lane][8]  hW1 A-frags (k 16->32 zero-pad)
//   [8192,  16384)  w1fp: same for fW1
//   [16384, 81920)  w2hp: [16 ob][8 s][64][8]  hW2 A-frags, khid-permuted
//   [81920,147456)  w2fp: same for fW2
//   [147456,151552) w3fp: [8 s][64][8]         fW3 A-frags, khid-permuted

typedef __attribute__((ext_vector_type(8))) short short8;       // 8 bf16 (4 VGPR)
typedef __attribute__((ext_vector_type(4))) float floatx4;      // MFMA C/D
typedef __attribute__((ext_vector_type(4))) unsigned int uintx4;

static __device__ __forceinline__ unsigned short f2bf(float x) {
  union { float f; uint32_t u; } v; v.f = x;
  return (unsigned short)((v.u + 0x7FFFu + ((v.u >> 16) & 1u)) >> 16);  // RNE
}
static __device__ __forceinline__ uint32_t packpair(float a, float b) {
  return (uint32_t)f2bf(a) | ((uint32_t)f2bf(b) << 16);
}
static __device__ __forceinline__ float unpklo(uint32_t u) {
  union { uint32_t u; float f; } v; v.u = u << 16;
  return v.f;
}
static __device__ __forceinline__ float unpkhi(uint32_t u) {
  union { uint32_t u; float f; } v; v.u = u & 0xffff0000u;
  return v.f;
}
// clamped Pade(7,6) tanh: max err ~7e-4, pure FMA + one v_rcp_f32
static __device__ __forceinline__ float tanh_fast(float x) {
  float cx = fminf(4.0f, fmaxf(-4.0f, x));
  float x2 = cx * cx;
  float num = cx * (135135.0f + x2 * (17325.0f + x2 * (378.0f + x2)));
  float den = 135135.0f + x2 * (62370.0f + x2 * (3150.0f + 28.0f * x2));
  return num * __builtin_amdgcn_rcpf(den);
}
static __device__ __forceinline__ floatx4 mfma16(short8 a, short8 b, floatx4 c) {
  return __builtin_amdgcn_mfma_f32_16x16x32_bf16(a, b, c, 0, 0, 0);
}
static __device__ __forceinline__ short8 asfrag(uintx4 u) {
  union { uintx4 u; short8 s; } v; v.u = u;
  return v.s;
}
// async global->LDS, 16B/lane. LDS dest: wave-uniform base + lane*16.
static __device__ __forceinline__ void gload_lds16(const unsigned short* g,
                                                   unsigned short* l) {
  __builtin_amdgcn_global_load_lds(
      (const __attribute__((address_space(1))) unsigned int*)g,
      (__attribute__((address_space(3))) unsigned int*)l, 16, 0, 0);
}

__global__ __launch_bounds__(256) void prep_kernel(
    const float* __restrict__ hW1, const float* __restrict__ hW2,
    const float* __restrict__ fW1, const float* __restrict__ fW2,
    const float* __restrict__ fW3, unsigned short* __restrict__ ws) {
  int i = blockIdx.x * 256 + threadIdx.x;  // grid covers [0, 65536)
  {
    int ob = i >> 12, s = (i >> 9) & 7, lane = (i >> 3) & 63, j = i & 7;
    int m = ob * 16 + (lane & 15), kg = lane >> 4;
    int k = 32 * s + 16 * (j >> 2) + 4 * kg + (j & 3);   // khid permutation
    ws[16384 + i] = f2bf(hW2[m * 256 + k]);
    ws[81920 + i] = f2bf(fW2[m * 256 + k]);
  }
  if (i < 8192) {
    int ob = i >> 9, lane = (i >> 3) & 63, j = i & 7;
    int m = ob * 16 + (lane & 15), kg = lane >> 4;
    unsigned short vh = 0, vf = 0;
    if (kg < 2) { int k = kg * 8 + j; vh = f2bf(hW1[m * 16 + k]); vf = f2bf(fW1[m * 16 + k]); }
    ws[i] = vh;
    ws[8192 + i] = vf;
  }
  if (i < 4096) {
    int s = i >> 9, lane = (i >> 3) & 63, j = i & 7;
    int m = lane & 15, kg = lane >> 4;
    int k = 32 * s + 16 * (j >> 2) + 4 * kg + (j & 3);
    ws[147456 + i] = f2bf(fW3[m * 256 + k]);
  }
}

__global__ __launch_bounds__(256, 2) void flexhnn_kernel(
    const float* __restrict__ z,
    const float* __restrict__ hb1, const float* __restrict__ hb2,
    const float* __restrict__ fb1, const float* __restrict__ fb2,
    const float* __restrict__ fb3,
    const unsigned short* __restrict__ ws,
    float* __restrict__ out) {
  // per-wave private s1 stash: [wave][strip][i=ob*2+p][lane] dwords (64 KiB),
  // 2 lanes/bank = free. + 2x8KB weight-chunk double buffer (16 KiB) = 80 KiB.
  __shared__ uint32_t s1_lds[4][2][32][64];
  __shared__ __align__(16) unsigned short wbuf[2][8][64][8];

  const int tid = threadIdx.x, lane = tid & 63, wave = tid >> 6;
  const int c = lane & 15, kg = lane >> 4;
  const int b0 = (blockIdx.x * 4 + wave) * 32;

  const unsigned short* w1hp = ws;
  const unsigned short* w1fp = ws + 8192;
  const unsigned short* w2hp = ws + 16384;
  const unsigned short* w2fp = ws + 81920;
  const unsigned short* w3fp = ws + 147456;

  const int s0 = wave * 2;  // this wave stages frags {s0, s0+1} of each chunk

  // ---- stage chunk 0 (w2hp ob=0) immediately; hides under phases 0-1 ----
  gload_lds16(w2hp + (s0 * 64 + lane) * 8,       &wbuf[0][s0][0][0]);
  gload_lds16(w2hp + ((s0 + 1) * 64 + lane) * 8, &wbuf[0][s0 + 1][0][0]);

  // ---- phase 0: z B-frags for the two strips (K=16 zero-padded to 32) ----
  short8 zf[2];
  zf[0] = (short8){0,0,0,0,0,0,0,0};
  zf[1] = (short8){0,0,0,0,0,0,0,0};
  if (kg < 2) {
#pragma unroll
    for (int st = 0; st < 2; ++st) {
      const float* zr = z + (size_t)(b0 + st * 16 + c) * 16 + kg * 8;
      uintx4 u;
      u.x = packpair(zr[0], zr[1]); u.y = packpair(zr[2], zr[3]);
      u.z = packpair(zr[4], zr[5]); u.w = packpair(zr[6], zr[7]);
      zf[st] = asfrag(u);
    }
  }

  // ---- phase 1: a1 = z@hW1^T; t1 -> B-frags (regs), s1 -> private LDS ----
  uintx4 t1v[2][8];
#pragma unroll
  for (int ob = 0; ob < 16; ++ob) {
    short8 wf = *reinterpret_cast<const short8*>(w1hp + (ob * 64 + lane) * 8);
    floatx4 bias = *reinterpret_cast<const floatx4*>(hb1 + ob * 16 + kg * 4);
#pragma unroll
    for (int st = 0; st < 2; ++st) {
      floatx4 a = mfma16(wf, zf[st], bias);
      float t0 = tanh_fast(a[0]), t1_ = tanh_fast(a[1]);
      float t2 = tanh_fast(a[2]), t3 = tanh_fast(a[3]);
      t1v[st][ob >> 1][(ob & 1) * 2 + 0] = packpair(t0, t1_);
      t1v[st][ob >> 1][(ob & 1) * 2 + 1] = packpair(t2, t3);
      s1_lds[wave][st][ob * 2 + 0][lane] = packpair(1.0f - t0 * t0, 1.0f - t1_ * t1_);
      s1_lds[wave][st][ob * 2 + 1][lane] = packpair(1.0f - t2 * t2, 1.0f - t3 * t3);
    }
  }
  __syncthreads();  // chunk 0 landed block-wide (s1 is wave-private, no sync need)

  // ---- phase 2: a2 = t1@hW2^T (s2 transient); f1 = z@fW1^T; fmix -> frags ----
  uintx4 fmv[2][8];
#pragma unroll
  for (int ob = 0; ob < 16; ++ob) {
    {  // stage chunk ob+1 (w2hp ob+1, or w2fp 0 when ob==15)
      const int t = ob + 1;
      const unsigned short* base = (t < 16) ? (w2hp + t * 4096) : (w2fp + (t - 16) * 4096);
      gload_lds16(base + (s0 * 64 + lane) * 8,       &wbuf[t & 1][s0][0][0]);
      gload_lds16(base + ((s0 + 1) * 64 + lane) * 8, &wbuf[t & 1][s0 + 1][0][0]);
    }
    floatx4 b2 = *reinterpret_cast<const floatx4*>(hb2 + ob * 16 + kg * 4);
    floatx4 a[2] = {b2, b2};
#pragma unroll
    for (int s = 0; s < 8; ++s) {
      short8 wf = *reinterpret_cast<const short8*>(&wbuf[ob & 1][s][lane][0]);
      a[0] = mfma16(wf, asfrag(t1v[0][s]), a[0]);
      a[1] = mfma16(wf, asfrag(t1v[1][s]), a[1]);
    }
    short8 w1 = *reinterpret_cast<const short8*>(w1fp + (ob * 64 + lane) * 8);
    floatx4 bf1 = *reinterpret_cast<const floatx4*>(fb1 + ob * 16 + kg * 4);
#pragma unroll
    for (int st = 0; st < 2; ++st) {
      floatx4 f = mfma16(w1, zf[st], bf1);
      float fm[4];
#pragma unroll
      for (int r = 0; r < 4; ++r) {
        float t2 = tanh_fast(a[st][r]);
        float s2 = 1.0f - t2 * t2;
        float fv = f[r];
        fm[r] = 0.5f * (fv * s2 + tanh_fast(fv));
      }
      fmv[st][ob >> 1][(ob & 1) * 2 + 0] = packpair(fm[0], fm[1]);
      fmv[st][ob >> 1][(ob & 1) * 2 + 1] = packpair(fm[2], fm[3]);
    }
    __syncthreads();  // all waves done reading wbuf[ob&1]; chunk ob+1 landed
  }

  // ---- phase 3: f2 = fmix@fW2^T; fmix2 = 0.5*(f2*s1 + tanh(f2)) -> frags ----
  uintx4 gv[2][8];
#pragma unroll
  for (int ob = 0; ob < 16; ++ob) {
    if (ob < 15) {  // stage chunk 17+ob (w2fp ob+1)
      const unsigned short* base = w2fp + (ob + 1) * 4096;
      gload_lds16(base + (s0 * 64 + lane) * 8,       &wbuf[(ob + 1) & 1][s0][0][0]);
      gload_lds16(base + ((s0 + 1) * 64 + lane) * 8, &wbuf[(ob + 1) & 1][s0 + 1][0][0]);
    }
    floatx4 bf2 = *reinterpret_cast<const floatx4*>(fb2 + ob * 16 + kg * 4);
    floatx4 a[2] = {bf2, bf2};
#pragma unroll
    for (int s = 0; s < 8; ++s) {
      short8 wf = *reinterpret_cast<const short8*>(&wbuf[ob & 1][s][lane][0]);
      a[0] = mfma16(wf, asfrag(fmv[0][s]), a[0]);
      a[1] = mfma16(wf, asfrag(fmv[1][s]), a[1]);
    }
#pragma unroll
    for (int st = 0; st < 2; ++st) {
      uint32_t sp0 = s1_lds[wave][st][ob * 2 + 0][lane];
      uint32_t sp1 = s1_lds[wave][st][ob * 2 + 1][lane];
      float s1a = unpklo(sp0), s1b = unpkhi(sp0), s1c = unpklo(sp1), s1d = unpkhi(sp1);
      float f0 = a[st][0], f1_ = a[st][1], f2_ = a[st][2], f3 = a[st][3];
      float g0 = 0.5f * (f0 * s1a + tanh_fast(f0));
      float g1 = 0.5f * (f1_ * s1b + tanh_fast(f1_));
      float g2 = 0.5f * (f2_ * s1c + tanh_fast(f2_));
      float g3 = 0.5f * (f3 * s1d + tanh_fast(f3));
      gv[st][ob >> 1][(ob & 1) * 2 + 0] = packpair(g0, g1);
      gv[st][ob >> 1][(ob & 1) * 2 + 1] = packpair(g2, g3);
    }
    if (ob < 15) __syncthreads();  // last iteration: no one overwrites wbuf
  }

  // ---- phase 4: f3 = fmix2@fW3^T (16 out rows, w3 from global); write ----
  {
    floatx4 b3 = *reinterpret_cast<const floatx4*>(fb3 + kg * 4);
    floatx4 o[2] = {b3, b3};
#pragma unroll
    for (int s = 0; s < 8; ++s) {
      short8 wf = *reinterpret_cast<const short8*>(w3fp + (s * 64 + lane) * 8);
      o[0] = mfma16(wf, asfrag(gv[0][s]), o[0]);
      o[1] = mfma16(wf, asfrag(gv[1][s]), o[1]);
    }
    // lane holds f rows o = 4*kg + r. o<8 -> out col o+8 = -f; o>=8 -> col o-8 = +f.
    const int off = (kg < 2) ? (kg * 4 + 8) : (kg * 4 - 8);
    const float sgn = (kg < 2) ? -1.0f : 1.0f;
#pragma unroll
    for (int st = 0; st < 2; ++st) {
      float4 stv;
      stv.x = sgn * o[st][0]; stv.y = sgn * o[st][1];
      stv.z = sgn * o[st][2]; stv.w = sgn * o[st][3];
      *reinterpret_cast<float4*>(out + (size_t)(b0 + st * 16 + c) * 16 + off) = stv;
    }
  }
}

extern "C" void kernel_launch(void* const* d_in, const int* in_sizes, int n_in,
                              void* d_out, int out_size, void* d_ws, size_t ws_size,
                              hipStream_t stream) {
  const float* z   = (const float*)d_in[1];
  const float* hW1 = (const float*)d_in[2];
  const float* hb1 = (const float*)d_in[3];
  const float* hW2 = (const float*)d_in[4];
  const float* hb2 = (const float*)d_in[5];
  const float* fW1 = (const float*)d_in[6];
  const float* fb1 = (const float*)d_in[7];
  const float* fW2 = (const float*)d_in[8];
  const float* fb2 = (const float*)d_in[9];
  const float* fW3 = (const float*)d_in[10];
  const float* fb3 = (const float*)d_in[11];
  unsigned short* ws = (unsigned short*)d_ws;
  float* out = (float*)d_out;

  hipLaunchKernelGGL(prep_kernel, dim3(256), dim3(256), 0, stream,
                     hW1, hW2, fW1, fW2, fW3, ws);
  // 131072 rows / (4 waves * 32 rows) = 1024 blocks
  hipLaunchKernelGGL(flexhnn_kernel, dim3(1024), dim3(256), 0, stream,
                     z, hb1, hb2, fb1, fb2, fb3, (const unsigned short*)ws, out);
}